// Round 14
// baseline (78.602 us; speedup 1.0000x reference)
//
#include <hip/hip_runtime.h>

// AdderNet 2D: out[n,f,h,w] = -sum_{c,kh,kw} |W[f,c,kh,kw] - xpad[n,c,h+kh,w+kw]|
// x: (16,64,14,14) fp32, W: (64,64,3,3) fp32, out: (16,64,14,14) fp32
//
// R14: CODE-SIZE attack. Every single-pass variant (R4..R13, all ~29us)
// shared one trait: ~20KB fully-unrolled bodies. Rep-loop diagnostics
// (R8/R12) show marginal pass cost 8.4-9us with a ~20us one-time
// intercept, invariant to epilogue/staging changes -> cold-I$ streaming
// after the 256MB poison fill evicts L2. Fix: ROLL the hot loop
// (12 x ~100 instr ~ 2.5KB). W must be dynamically indexed -> move W to
// LDS (transposed wl[(c*9+kk)*17+f]: hot reads 2-way bank = free;
// dynamic LDS indexing can't demote registers, unlike Wr[] in R8).
// x tile CSTRIDE=52 (16B-aligned, c_sub banks {0,16} = free broadcast).
// LDS 51.25KB -> 3 blocks/CU. (256,1) = proven no-spill (R12: VGPR 112).

#define N_ 16
#define C_ 64
#define F_ 64
#define P_ 196
#define CSTRIDE 52     // dwords per channel in xs (48 data + pad, mult of 4)

__global__ __launch_bounds__(256, 1) void adder2d_kernel(
    const float* __restrict__ x, const float* __restrict__ w,
    float* __restrict__ out)
{
    __shared__ __align__(16) float xs[C_ * CSTRIDE];   // 13,312 B
    __shared__ float wl[9792];                          // 39,168 B

    const int tid = threadIdx.x;        // 0..255
    const int row = blockIdx.x;         // 0..13 output row
    const int n   = blockIdx.y;         // 0..15
    const int fg  = blockIdx.z;         // 0..3 -> filters fg*16..fg*16+15

    // ---- stage x: 64ch x 3rows x 16cols (zero-padded), rolled ----
    #pragma unroll 1
    for (int i = 0; i < 12; ++i) {
        const int idx = tid + 256 * i;          // 0..3071
        const int c   = idx / 48;
        const int rem = idx - c * 48;
        const int r   = rem >> 4;               // 0..2
        const int col = rem & 15;               // 0..15 padded col
        const int ir  = row + r - 1;            // input row, -1..14
        float v = 0.f;
        if (col >= 1 && col <= 14 && ir >= 0 && ir <= 13)
            v = x[(n * C_ + c) * P_ + ir * 14 + (col - 1)];
        xs[c * CSTRIDE + r * 16 + col] = v;
    }

    // ---- stage W slice (16f x 64c x 9) transposed: wl[(c*9+kk)*17+f] ----
    #pragma unroll 1
    for (int i = 0; i < 36; ++i) {
        const int s   = tid + 256 * i;          // 0..9215
        const int fl  = s / 576;                // 0..15 filter
        const int rem = s - fl * 576;           // c*9+kk
        wl[rem * 17 + fl] = w[(fg * 16 + fl) * 576 + rem];
    }

    const int f_local = tid & 15;               // 0..15
    const int c_sub   = (tid >> 4) & 3;         // 0..3
    const int wv      = tid >> 6;               // wave 0..3
    const int cb      = wv * 16 + c_sub * 4;    // lane's 4 channels

    float acc[14];
    #pragma unroll
    for (int p = 0; p < 14; ++p) acc[p] = 0.f;

    __syncthreads();

    // ---- hot loop, ROLLED: 4 cl x 3 kh iterations ----
    const float* xb = xs + cb * CSTRIDE;
    const float* wb = wl + (cb * 9) * 17 + f_local;
    #pragma unroll 1
    for (int cl = 0; cl < 4; ++cl) {
        #pragma unroll 1
        for (int kh = 0; kh < 3; ++kh) {
            const float4* rp = (const float4*)(xb + cl * CSTRIDE + kh * 16);
            float4 q0 = rp[0], q1 = rp[1], q2 = rp[2], q3 = rp[3];
            const float* wp = wb + (cl * 9 + kh * 3) * 17;
            float w0 = wp[0], w1 = wp[17], w2 = wp[34];
            float xr[16] = {q0.x, q0.y, q0.z, q0.w,  q1.x, q1.y, q1.z, q1.w,
                            q2.x, q2.y, q2.z, q2.w,  q3.x, q3.y, q3.z, q3.w};
            #pragma unroll
            for (int p = 0; p < 14; ++p)
                acc[p] += fabsf(w0 - xr[p]) + fabsf(w1 - xr[p + 1])
                        + fabsf(w2 - xr[p + 2]);
        }
    }

    // ---- reduce over c_sub (lanes ^16, ^32) ----
    #pragma unroll
    for (int p = 0; p < 14; ++p) {
        acc[p] += __shfl_xor(acc[p], 16);
        acc[p] += __shfl_xor(acc[p], 32);
    }

    // ---- cross-wave partials: alias xs (everyone is past xs reads) ----
    __syncthreads();
    float* part = xs;                   // [wv][f_local][15]
    if (c_sub == 0) {
        #pragma unroll
        for (int p = 0; p < 14; ++p)
            part[(wv * 16 + f_local) * 15 + p] = acc[p];
    }
    __syncthreads();

    // ---- final 4-way sum + direct store: 224 outputs ----
    if (tid < 224) {
        const int f  = tid / 14;
        const int px = tid - f * 14;
        float s = part[(0 * 16 + f) * 15 + px] + part[(1 * 16 + f) * 15 + px]
                + part[(2 * 16 + f) * 15 + px] + part[(3 * 16 + f) * 15 + px];
        out[(n * F_ + fg * 16 + f) * P_ + row * 14 + px] = -s;
    }
}

extern "C" void kernel_launch(void* const* d_in, const int* in_sizes, int n_in,
                              void* d_out, int out_size, void* d_ws, size_t ws_size,
                              hipStream_t stream) {
    const float* x = (const float*)d_in[0];
    const float* w = (const float*)d_in[1];
    float* out = (float*)d_out;
    dim3 grid(14, N_, 4);
    adder2d_kernel<<<grid, 256, 0, stream>>>(x, w, out);
}